// Round 3
// baseline (929.578 us; speedup 1.0000x reference)
//
#include <hip/hip_runtime.h>

// Problem dims (fixed)
#define HID_   128
#define BB_    256
#define TT_    300
#define DIN_   700
#define LL_    4
#define NOUT_  20
#define NROWS_ (BB_*TT_)          // 76800

// d_out layout (floats): out[256*20] | hid4_mem[256*301*128] | hid4_spk[...] | A_norm[1]
#define OUT_OFF   0
#define HMEM_OFF  5120
#define HSPK_OFF  (5120 + 256*301*128)
#define ANORM_OFF (5120 + 2*256*301*128)

// Pre-split fragment buffers (ushort elements)
#define W1ELTS (22*4096)     // 90112  : w_in  22 k-chunks x [nt][l15][kg*8+j]
#define A2ELTS (4*4*4096)    // 65536  : A_w   4 layers x 4 k-chunks x same
#define PRESPLIT_FLOATS ((2*W1ELTS + 2*A2ELTS)/2)   // 155648 floats = 622592 B

typedef __attribute__((ext_vector_type(8))) short  bfrag;   // 8 bf16 (4 VGPR)
typedef __attribute__((ext_vector_type(4))) float  f32x4;   // MFMA C/D

// f32 -> bf16 (RNE) bit helpers
__device__ __forceinline__ unsigned short f2bf(float f) {
    unsigned int u = __float_as_uint(f);
    return (unsigned short)((u + 0x7fffu + ((u >> 16) & 1u)) >> 16);
}
__device__ __forceinline__ float bf2f(unsigned short h) {
    return __uint_as_float(((unsigned int)h) << 16);
}
__device__ __forceinline__ void split2(float v, unsigned short& hi, unsigned short& lo) {
    hi = f2bf(v);
    lo = f2bf(v - bf2f(hi));
}

// ---------------------------------------------------------------------------
// K0: one-time pre-split of w_in and A_w into MFMA B-fragment order:
//   flat = ((ks*8 + nt)*16 + l15)*32 + kg*8 + j   holds  W[ks*32+kg*8+j][nt*16+l15]
// Grid 608*256 == 90112 + 65536 exactly.
// ---------------------------------------------------------------------------
__global__ __launch_bounds__(256)
void k0_presplit(const float* __restrict__ w, const float* __restrict__ Aw,
                 unsigned short* __restrict__ w1hi, unsigned short* __restrict__ w1lo,
                 unsigned short* __restrict__ a2hi, unsigned short* __restrict__ a2lo)
{
    const int f = blockIdx.x * 256 + threadIdx.x;
    if (f < W1ELTS) {
        const int ks = f >> 12, r = f & 4095;
        const int nt = r >> 9, l15 = (r >> 5) & 15, kk = r & 31;
        const int k = ks * 32 + kk, n = nt * 16 + l15;
        const float v = (k < DIN_) ? w[(long)k * HID_ + n] : 0.f;
        unsigned short hi, lo; split2(v, hi, lo);
        w1hi[f] = hi; w1lo[f] = lo;
    } else {
        const int g = f - W1ELTS;              // 0..65535
        const int l = g >> 14, r2 = g & 16383;
        const int ks = r2 >> 12, r = r2 & 4095;
        const int nt = r >> 9, l15 = (r >> 5) & 15, kk = r & 31;
        const int k = ks * 32 + kk, n = nt * 16 + l15;
        const float v = Aw[(long)l * 16384 + (long)k * HID_ + n];
        unsigned short hi, lo; split2(v, hi, lo);
        a2hi[g] = hi; a2lo[g] = lo;
    }
}

// ---------------------------------------------------------------------------
// K1 v3 (register fragments, no LDS, 1 m-tile/wave for 2x occupancy):
// inp = x @ w_in + b_in. Grid 1200 x 256thr; wave owns 16 rows.
// Same per-acc MFMA sequence as v2 -> bitwise identical output.
// ---------------------------------------------------------------------------
__global__ __launch_bounds__(256, 4)
void k1_reg(const float* __restrict__ x,
            const unsigned short* __restrict__ whi,
            const unsigned short* __restrict__ wlo,
            const float* __restrict__ bin, float* __restrict__ inp)
{
    const int tid  = threadIdx.x;
    const int wave = tid >> 6;
    const int lane = tid & 63;
    const int l15  = lane & 15;
    const int kg   = lane >> 4;
    const long m0  = (long)blockIdx.x * 64 + wave * 16;

    f32x4 acc[8];
#pragma unroll
    for (int nt = 0; nt < 8; ++nt) {
        const float bv = bin[nt * 16 + l15];
        acc[nt] = (f32x4){bv, bv, bv, bv};
    }

    const int foff = l15 * 32 + kg * 8;

    for (int ks = 0; ks < 22; ++ks) {
        const int kbase = ks * 32 + kg * 8;

        bfrag ahi, alo;
        const float* __restrict__ xr = x + (m0 + l15) * (long)DIN_ + kbase;
        if (kbase + 7 < DIN_) {
            const float4 p0 = *(const float4*)(xr);
            const float4 p1 = *(const float4*)(xr + 4);
            float vv[8] = {p0.x, p0.y, p0.z, p0.w, p1.x, p1.y, p1.z, p1.w};
#pragma unroll
            for (int j = 0; j < 8; ++j) {
                unsigned short hi, lo; split2(vv[j], hi, lo);
                ahi[j] = (short)hi; alo[j] = (short)lo;
            }
        } else {
#pragma unroll
            for (int j = 0; j < 8; ++j) {
                float v = (kbase + j < DIN_) ? xr[j] : 0.f;
                unsigned short hi, lo; split2(v, hi, lo);
                ahi[j] = (short)hi; alo[j] = (short)lo;
            }
        }

        const unsigned short* __restrict__ wh = whi + (long)ks * 4096 + foff;
        const unsigned short* __restrict__ wl = wlo + (long)ks * 4096 + foff;
#pragma unroll
        for (int nt = 0; nt < 8; ++nt) {
            const bfrag bhi = *(const bfrag*)(wh + nt * 512);
            const bfrag blo = *(const bfrag*)(wl + nt * 512);
            acc[nt] = __builtin_amdgcn_mfma_f32_16x16x32_bf16(ahi, bhi, acc[nt], 0, 0, 0);
            acc[nt] = __builtin_amdgcn_mfma_f32_16x16x32_bf16(ahi, blo, acc[nt], 0, 0, 0);
            acc[nt] = __builtin_amdgcn_mfma_f32_16x16x32_bf16(alo, bhi, acc[nt], 0, 0, 0);
        }
    }

#pragma unroll
    for (int nt = 0; nt < 8; ++nt) {
        const int col = nt * 16 + l15;
#pragma unroll
        for (int reg = 0; reg < 4; ++reg)
            inp[(m0 + kg * 4 + reg) * (long)HID_ + col] = acc[nt][reg];
    }
}

// ---------------------------------------------------------------------------
// K23: fused reservoir drive (MFMA) + LIF scan. Block = (l, b); 4 waves.
// Per 64-t chunk: each wave MFMAs one 16-t m-tile x 128 h (same split-bf16
// sequence as k2_reg -> bitwise identical xs), stages chunk in LDS, then
// threads 0..127 advance the sequential scan 64 steps. xs never hits HBM.
// ---------------------------------------------------------------------------
#define TC_ 64
__global__ __launch_bounds__(256, 4)
void k23_fused(const float* __restrict__ inp,
               const unsigned short* __restrict__ ahiP,
               const unsigned short* __restrict__ aloP,
               const float* __restrict__ Ab, const float* __restrict__ thr,
               const float* __restrict__ dec, const float* __restrict__ rstv,
               const float* __restrict__ mem0, float* __restrict__ rates,
               float* __restrict__ omem, float* __restrict__ ospk)
{
    __shared__ float xls[TC_ * 132];

    const int tid  = threadIdx.x;
    const int wave = tid >> 6;
    const int lane = tid & 63;
    const int l15  = lane & 15;
    const int kg   = lane >> 4;
    const int bid  = blockIdx.x;
    const int l    = bid >> 8;
    const int b    = bid & 255;
    const int foff = l15 * 32 + kg * 8;

    const unsigned short* __restrict__ ph = ahiP + (long)l * 16384;
    const unsigned short* __restrict__ pl = aloP + (long)l * 16384;
    const float* __restrict__ ibase = inp + (long)b * TT_ * HID_;

    // scan state (threads 0..127 only)
    const int h = tid;
    const bool isScan = (tid < 128);
    const bool last   = (l == 3);
    float mem = 0.f, spk = 0.f, cnt = 0.f, th = 0.f, dc = 0.f, rs = 0.f;
    float* __restrict__ om = omem + (long)b * 301 * 128 + (h & 127);
    float* __restrict__ os = ospk + (long)b * 301 * 128 + (h & 127);
    if (isScan) {
        th  = thr[h]; dc = dec[h]; rs = rstv[h];
        mem = mem0[((long)l * 256 + b) * 128 + h];
        if (last) { om[0] = mem; os[0] = 0.f; }
    }

    for (int t0 = 0; t0 < TT_; t0 += TC_) {
        // ---- drive GEMM for rows [t0 .. t0+63] (wave -> 16-t m-tile)
        f32x4 acc[8];
#pragma unroll
        for (int nt = 0; nt < 8; ++nt) {
            const float bv = Ab[l * HID_ + nt * 16 + l15];
            acc[nt] = (f32x4){bv, bv, bv, bv};
        }

        const int rbase = t0 + wave * 16;
#pragma unroll
        for (int ks = 0; ks < 4; ++ks) {
            int row = rbase + l15;
            if (row > TT_ - 1) row = TT_ - 1;     // clamp (values unused by scan)
            const float* __restrict__ ir = ibase + (long)row * HID_ + ks * 32 + kg * 8;
            const float4 p0 = *(const float4*)(ir);
            const float4 p1 = *(const float4*)(ir + 4);
            float vv[8] = {p0.x, p0.y, p0.z, p0.w, p1.x, p1.y, p1.z, p1.w};
            bfrag xhi, xlo;
#pragma unroll
            for (int j = 0; j < 8; ++j) {
                unsigned short hi, lo; split2(vv[j], hi, lo);
                xhi[j] = (short)hi; xlo[j] = (short)lo;
            }

            const unsigned short* __restrict__ bh = ph + ks * 4096 + foff;
            const unsigned short* __restrict__ bl = pl + ks * 4096 + foff;
#pragma unroll
            for (int nt = 0; nt < 8; ++nt) {
                const bfrag bhi = *(const bfrag*)(bh + nt * 512);
                const bfrag blo = *(const bfrag*)(bl + nt * 512);
                acc[nt] = __builtin_amdgcn_mfma_f32_16x16x32_bf16(xhi, bhi, acc[nt], 0, 0, 0);
                acc[nt] = __builtin_amdgcn_mfma_f32_16x16x32_bf16(xhi, blo, acc[nt], 0, 0, 0);
                acc[nt] = __builtin_amdgcn_mfma_f32_16x16x32_bf16(xlo, bhi, acc[nt], 0, 0, 0);
            }
        }

        // ---- stage chunk to LDS: local row = wave*16 + kg*4 + reg, col = nt*16+l15
#pragma unroll
        for (int nt = 0; nt < 8; ++nt) {
            const int col = nt * 16 + l15;
#pragma unroll
            for (int reg = 0; reg < 4; ++reg)
                xls[(wave * 16 + kg * 4 + reg) * 132 + col] = acc[nt][reg];
        }
        __syncthreads();

        // ---- sequential scan over this chunk
        if (isScan) {
            const int tmax = (TT_ - t0 < TC_) ? (TT_ - t0) : TC_;
            for (int tt = 0; tt < tmax; ++tt) {
                const float v = xls[tt * 132 + h];
                mem = rs * spk + mem * dc * (1.f - spk) + v;
                spk = (mem - th > 0.f) ? 1.f : 0.f;
                cnt += spk;
                if (last) {
                    om[(long)(t0 + tt + 1) * 128] = mem;
                    os[(long)(t0 + tt + 1) * 128] = spk;
                }
            }
        }
        __syncthreads();
    }

    if (isScan)
        rates[((long)l * 256 + b) * 128 + h] = cnt * (1.f / 300.f);
}

// ---------------------------------------------------------------------------
// K1 (legacy MFMA, LDS-staged) — fallback path only.
// ---------------------------------------------------------------------------
__global__ __launch_bounds__(256, 2)
void k1_mfma(const float* __restrict__ x, const float* __restrict__ w,
             const float* __restrict__ bin, float* __restrict__ inp)
{
    __shared__ unsigned short whi[128 * 40];
    __shared__ unsigned short wlo[128 * 40];

    const int tid  = threadIdx.x;
    const int wave = tid >> 6;
    const int lane = tid & 63;
    const int l15  = lane & 15;
    const int kg   = lane >> 4;
    const long m0  = (long)blockIdx.x * 64 + wave * 16;
    const long arow = m0 + l15;

    f32x4 acc[8];
#pragma unroll
    for (int nt = 0; nt < 8; ++nt) {
        const float bv = bin[nt * 16 + l15];
        acc[nt] = (f32x4){bv, bv, bv, bv};
    }

    for (int ks = 0; ks < 22; ++ks) {
        const int k0 = ks * 32;
        const int lim = (700 - k0) * 128;
        const float* __restrict__ wsrc = w + (long)k0 * 128;
#pragma unroll
        for (int j = 0; j < 16; ++j) {
            const int i = tid + j * 256;
            const int kk = i >> 7, nn = i & 127;
            float v = (i < lim) ? wsrc[i] : 0.f;
            unsigned short hi, lo;
            split2(v, hi, lo);
            whi[nn * 40 + kk] = hi;
            wlo[nn * 40 + kk] = lo;
        }
        __syncthreads();

        bfrag ahi, alo;
        const int kbase = k0 + kg * 8;
        const float* __restrict__ xr = x + arow * (long)DIN_ + kbase;
        if (kbase + 7 < 700) {
            const float4 p0 = *(const float4*)(xr);
            const float4 p1 = *(const float4*)(xr + 4);
            float vv[8] = {p0.x, p0.y, p0.z, p0.w, p1.x, p1.y, p1.z, p1.w};
#pragma unroll
            for (int j = 0; j < 8; ++j) {
                unsigned short hi, lo; split2(vv[j], hi, lo);
                ahi[j] = (short)hi; alo[j] = (short)lo;
            }
        } else {
#pragma unroll
            for (int j = 0; j < 8; ++j) {
                float v = (kbase + j < 700) ? xr[j] : 0.f;
                unsigned short hi, lo; split2(v, hi, lo);
                ahi[j] = (short)hi; alo[j] = (short)lo;
            }
        }

#pragma unroll
        for (int nt = 0; nt < 8; ++nt) {
            const int boff = (nt * 16 + l15) * 40 + kg * 8;
            const bfrag bhi = *(const bfrag*)&whi[boff];
            const bfrag blo = *(const bfrag*)&wlo[boff];
            acc[nt] = __builtin_amdgcn_mfma_f32_16x16x32_bf16(ahi, bhi, acc[nt], 0, 0, 0);
            acc[nt] = __builtin_amdgcn_mfma_f32_16x16x32_bf16(ahi, blo, acc[nt], 0, 0, 0);
            acc[nt] = __builtin_amdgcn_mfma_f32_16x16x32_bf16(alo, bhi, acc[nt], 0, 0, 0);
        }
        __syncthreads();
    }

#pragma unroll
    for (int nt = 0; nt < 8; ++nt) {
        const int col = nt * 16 + l15;
#pragma unroll
        for (int reg = 0; reg < 4; ++reg)
            inp[(m0 + kg * 4 + reg) * (long)HID_ + col] = acc[nt][reg];
    }
}

// ---------------------------------------------------------------------------
// K2 (legacy MFMA, LDS-staged) — fallback path only.
// ---------------------------------------------------------------------------
__global__ __launch_bounds__(256, 2)
void k2_mfma(const float* __restrict__ inp, const float* __restrict__ Aw,
             const float* __restrict__ Ab, float* __restrict__ xs,
             int lsel, long lstride)
{
    __shared__ unsigned short ahiS[128 * 72];
    __shared__ unsigned short aloS[128 * 72];

    const int tid  = threadIdx.x;
    const int wave = tid >> 6;
    const int lane = tid & 63;
    const int l15  = lane & 15;
    const int kg   = lane >> 4;
    const int l    = (lsel >= 0) ? lsel : (int)blockIdx.y;
    const long m0  = (long)blockIdx.x * 64 + wave * 16;
    const long arow = m0 + l15;
    const long lbase = (lsel >= 0) ? 0 : (long)l * lstride;

    f32x4 acc[8];
#pragma unroll
    for (int nt = 0; nt < 8; ++nt) {
        const float bv = Ab[l * 128 + nt * 16 + l15];
        acc[nt] = (f32x4){bv, bv, bv, bv};
    }

    const float* __restrict__ Al = Aw + (long)l * 128 * 128;

    for (int kc = 0; kc < 2; ++kc) {
        const float* __restrict__ asrc = Al + (long)kc * 64 * 128;
#pragma unroll
        for (int j = 0; j < 32; ++j) {
            const int i = tid + j * 256;
            const int kk = i >> 7, nn = i & 127;
            unsigned short hi, lo;
            split2(asrc[i], hi, lo);
            ahiS[nn * 72 + kk] = hi;
            aloS[nn * 72 + kk] = lo;
        }
        __syncthreads();

#pragma unroll
        for (int ks = 0; ks < 2; ++ks) {
            const int k0 = kc * 64 + ks * 32;
            bfrag ahi, alo;
            const float* __restrict__ ir = inp + arow * (long)HID_ + k0 + kg * 8;
            const float4 p0 = *(const float4*)(ir);
            const float4 p1 = *(const float4*)(ir + 4);
            float vv[8] = {p0.x, p0.y, p0.z, p0.w, p1.x, p1.y, p1.z, p1.w};
#pragma unroll
            for (int j = 0; j < 8; ++j) {
                unsigned short hi, lo; split2(vv[j], hi, lo);
                ahi[j] = (short)hi; alo[j] = (short)lo;
            }

#pragma unroll
            for (int nt = 0; nt < 8; ++nt) {
                const int boff = (nt * 16 + l15) * 72 + ks * 32 + kg * 8;
                const bfrag bhi = *(const bfrag*)&ahiS[boff];
                const bfrag blo = *(const bfrag*)&aloS[boff];
                acc[nt] = __builtin_amdgcn_mfma_f32_16x16x32_bf16(ahi, bhi, acc[nt], 0, 0, 0);
                acc[nt] = __builtin_amdgcn_mfma_f32_16x16x32_bf16(ahi, blo, acc[nt], 0, 0, 0);
                acc[nt] = __builtin_amdgcn_mfma_f32_16x16x32_bf16(alo, bhi, acc[nt], 0, 0, 0);
            }
        }
        __syncthreads();
    }

#pragma unroll
    for (int nt = 0; nt < 8; ++nt) {
        const int col = nt * 16 + l15;
#pragma unroll
        for (int reg = 0; reg < 4; ++reg)
            xs[(lbase + m0 + kg * 4 + reg) * (long)HID_ + col] = acc[nt][reg];
    }
}

// ---------------------------------------------------------------------------
// K3': elementwise scan over t — fallback path only.
// ---------------------------------------------------------------------------
__global__ __launch_bounds__(128, 4)
void k3_scan_split(const float* __restrict__ xs, const float* __restrict__ thr,
                   const float* __restrict__ dec, const float* __restrict__ rstv,
                   const float* __restrict__ mem0, float* __restrict__ rates,
                   float* __restrict__ omem, float* __restrict__ ospk,
                   int lsel, long lstride)
{
    const int h = threadIdx.x;
    int l, b;
    if (lsel >= 0) { l = lsel; b = blockIdx.x; }
    else           { l = blockIdx.x >> 8; b = blockIdx.x & 255; }

    const float th = thr[h];
    const float dc = dec[h];
    const float rs = rstv[h];

    float mem = mem0[((long)l * 256 + b) * 128 + h];
    float spk = 0.f;
    float cnt = 0.f;

    const bool last = (l == 3);
    float* __restrict__ om = omem + (long)b * 301 * 128 + h;
    float* __restrict__ os = ospk + (long)b * 301 * 128 + h;
    if (last) { om[0] = mem; os[0] = 0.f; }

    const float* __restrict__ p =
        xs + ((lsel >= 0 ? 0L : (long)l * lstride) + (long)b * TT_) * HID_ + h;

    for (int t0 = 0; t0 < TT_; t0 += 20) {
        float v[20];
#pragma unroll
        for (int j = 0; j < 20; ++j) v[j] = p[(long)(t0 + j) * HID_];
#pragma unroll
        for (int j = 0; j < 20; ++j) {
            mem = rs * spk + mem * dc * (1.f - spk) + v[j];
            spk = (mem - th > 0.f) ? 1.f : 0.f;
            cnt += spk;
            if (last) {
                om[(long)(t0 + j + 1) * 128] = mem;
                os[(long)(t0 + j + 1) * 128] = spk;
            }
        }
    }

    rates[((long)l * 256 + b) * 128 + h] = cnt * (1.f / 300.f);
}

// ---------------------------------------------------------------------------
// Legacy fused drive+scan (fallback when ws is tiny).
// ---------------------------------------------------------------------------
__global__ __launch_bounds__(128, 2)
void k3_fused(const float* __restrict__ inp, const float* __restrict__ Aw,
              const float* __restrict__ Ab, const float* __restrict__ thr,
              const float* __restrict__ dec, const float* __restrict__ rstv,
              const float* __restrict__ mem0, float* __restrict__ rates,
              float* __restrict__ omem, float* __restrict__ ospk)
{
    const int h = threadIdx.x;
    const int l = blockIdx.x & 3;
    const int b = blockIdx.x >> 2;

    float a[128];
#pragma unroll
    for (int k = 0; k < 128; ++k)
        a[k] = Aw[((long)l * 128 + k) * 128 + h];

    const float ab = Ab[l * 128 + h];
    const float th = thr[h];
    const float dc = dec[h];
    const float rs = rstv[h];

    float mem = mem0[((long)l * 256 + b) * 128 + h];
    float spk = 0.f, cnt = 0.f;

    const bool last = (l == 3);
    float* __restrict__ om = omem + (long)b * 301 * 128 + h;
    float* __restrict__ os = ospk + (long)b * 301 * 128 + h;
    if (last) { om[0] = mem; os[0] = 0.f; }

    const float* __restrict__ ip = inp + (long)b * 300 * 128;

    for (int t = 0; t < 300; ++t) {
        float acc = ab;
#pragma unroll
        for (int k = 0; k < 128; ++k)
            acc = fmaf(ip[k], a[k], acc);
        ip += 128;
        mem = rs * spk + mem * dc * (1.f - spk) + acc;
        spk = (mem - th > 0.f) ? 1.f : 0.f;
        cnt += spk;
        if (last) {
            om[(long)(t + 1) * 128] = mem;
            os[(long)(t + 1) * 128] = spk;
        }
    }
    rates[((long)l * 256 + b) * 128 + h] = cnt * (1.f / 300.f);
}

// ---------------------------------------------------------------------------
// K4: head. block per batch row b.
// ---------------------------------------------------------------------------
__global__ __launch_bounds__(256)
void k4_head(const float* __restrict__ rates, const float* __restrict__ fcw,
             const float* __restrict__ fcb, const float* __restrict__ wout,
             const float* __restrict__ bout, float* __restrict__ out)
{
    __shared__ float cat[512];
    const int b = blockIdx.x;
    const int tid = threadIdx.x;

    for (int c = tid; c < 512; c += 256) {
        const int l = c >> 7;
        const int k = c & 127;
        float s = fcb[l * 128 + k];
        const float* __restrict__ rp = rates + ((long)l * 256 + b) * 128;
        const float* __restrict__ wp = fcw + (long)l * 128 * 128 + k;
#pragma unroll 8
        for (int hh = 0; hh < 128; ++hh)
            s = fmaf(rp[hh], wp[(long)hh * 128], s);
        cat[c] = s > 0.f ? s : 0.f;
    }
    __syncthreads();

    if (tid < NOUT_) {
        float s = bout[tid];
#pragma unroll 8
        for (int c = 0; c < 512; ++c)
            s = fmaf(cat[c], wout[(long)c * NOUT_ + tid], s);
        out[(long)b * NOUT_ + tid] = s;
    }
}

// ---------------------------------------------------------------------------
// K5: A_norm = sum |A_w|. Single block.
// ---------------------------------------------------------------------------
__global__ __launch_bounds__(256)
void k5_anorm(const float* __restrict__ Aw, float* __restrict__ out)
{
    __shared__ float red[256];
    const int tid = threadIdx.x;
    float s = 0.f;
    for (int i = tid; i < LL_ * 128 * 128; i += 256)
        s += fabsf(Aw[i]);
    red[tid] = s;
    __syncthreads();
#pragma unroll
    for (int st = 128; st > 0; st >>= 1) {
        if (tid < st) red[tid] += red[tid + st];
        __syncthreads();
    }
    if (tid == 0) out[0] = red[0];
}

// ---------------------------------------------------------------------------
extern "C" void kernel_launch(void* const* d_in, const int* in_sizes, int n_in,
                              void* d_out, int out_size, void* d_ws, size_t ws_size,
                              hipStream_t stream)
{
    const float* x    = (const float*)d_in[0];
    const float* w_in = (const float*)d_in[1];
    const float* b_in = (const float*)d_in[2];
    const float* A_w  = (const float*)d_in[3];
    const float* A_b  = (const float*)d_in[4];
    const float* fc_w = (const float*)d_in[5];
    const float* fc_b = (const float*)d_in[6];
    const float* w_out= (const float*)d_in[7];
    const float* b_out= (const float*)d_in[8];
    const float* thr  = (const float*)d_in[9];
    const float* dec  = (const float*)d_in[10];
    const float* rst  = (const float*)d_in[11];
    const float* mem0 = (const float*)d_in[12];

    float* out = (float*)d_out;
    float* ws  = (float*)d_ws;

    const long INP_ELTS = (long)NROWS_ * HID_;
    const long XS_FULL  = 4L * NROWS_ * HID_;
    const long RATES    = 4L * 256 * 128;

    const size_t need_v3   = (size_t)(PRESPLIT_FLOATS + INP_ELTS + RATES) * 4;
    const size_t need_full = (size_t)(INP_ELTS + XS_FULL + RATES) * 4;
    const size_t need_perl = (size_t)(INP_ELTS + INP_ELTS + RATES) * 4;

    if (ws_size >= need_v3) {
        // --- v3 path: pre-split weights + LDS-free k1 + fused drive/scan ---
        unsigned short* us   = (unsigned short*)ws;
        unsigned short* w1hi = us;
        unsigned short* w1lo = us + W1ELTS;
        unsigned short* a2hi = us + 2 * W1ELTS;
        unsigned short* a2lo = us + 2 * W1ELTS + A2ELTS;
        float* inp   = ws + PRESPLIT_FLOATS;
        float* rates = inp + INP_ELTS;

        k0_presplit<<<608, 256, 0, stream>>>(w_in, A_w, w1hi, w1lo, a2hi, a2lo);
        k1_reg<<<1200, 256, 0, stream>>>(x, w1hi, w1lo, b_in, inp);
        k23_fused<<<1024, 256, 0, stream>>>(inp, a2hi, a2lo, A_b, thr, dec, rst,
                                            mem0, rates,
                                            out + HMEM_OFF, out + HSPK_OFF);
        k4_head<<<256, 256, 0, stream>>>(rates, fc_w, fc_b, w_out, b_out, out + OUT_OFF);
    } else if (ws_size >= need_full) {
        float* inp   = ws;
        float* xs    = ws + INP_ELTS;
        float* rates = xs + XS_FULL;
        k1_mfma<<<1200, 256, 0, stream>>>(x, w_in, b_in, inp);
        k2_mfma<<<dim3(1200, 4), 256, 0, stream>>>(inp, A_w, A_b, xs, -1, (long)NROWS_);
        k3_scan_split<<<1024, 128, 0, stream>>>(xs, thr, dec, rst, mem0, rates,
                                                out + HMEM_OFF, out + HSPK_OFF,
                                                -1, (long)NROWS_);
        k4_head<<<256, 256, 0, stream>>>(rates, fc_w, fc_b, w_out, b_out, out + OUT_OFF);
    } else if (ws_size >= need_perl) {
        float* inp   = ws;
        float* xs    = ws + INP_ELTS;
        float* rates = xs + INP_ELTS;
        k1_mfma<<<1200, 256, 0, stream>>>(x, w_in, b_in, inp);
        for (int l = 0; l < 4; ++l) {
            k2_mfma<<<dim3(1200, 1), 256, 0, stream>>>(inp, A_w, A_b, xs, l, 0L);
            k3_scan_split<<<256, 128, 0, stream>>>(xs, thr, dec, rst, mem0, rates,
                                                   out + HMEM_OFF, out + HSPK_OFF,
                                                   l, 0L);
        }
        k4_head<<<256, 256, 0, stream>>>(rates, fc_w, fc_b, w_out, b_out, out + OUT_OFF);
    } else {
        float* inp   = ws;
        float* rates = ws + INP_ELTS;
        k1_mfma<<<1200, 256, 0, stream>>>(x, w_in, b_in, inp);
        k3_fused<<<1024, 128, 0, stream>>>(inp, A_w, A_b, thr, dec, rst, mem0,
                                           rates, out + HMEM_OFF, out + HSPK_OFF);
        k4_head<<<256, 256, 0, stream>>>(rates, fc_w, fc_b, w_out, b_out, out + OUT_OFF);
    }

    k5_anorm<<<1, 256, 0, stream>>>(A_w, out + ANORM_OFF);
}

// Round 4
// 737.997 us; speedup vs baseline: 1.2596x; 1.2596x over previous
//
#include <hip/hip_runtime.h>

// Problem dims (fixed)
#define HID_   128
#define BB_    256
#define TT_    300
#define DIN_   700
#define LL_    4
#define NOUT_  20
#define NROWS_ (BB_*TT_)          // 76800

// d_out layout (floats): out[256*20] | hid4_mem[256*301*128] | hid4_spk[...] | A_norm[1]
#define OUT_OFF   0
#define HMEM_OFF  5120
#define HSPK_OFF  (5120 + 256*301*128)
#define ANORM_OFF (5120 + 2*256*301*128)

// Pre-split fragment buffers (ushort elements), lane-linear tile layout:
//   tile (ks,nt) = 512 ushorts; within tile: lane*8 + j  holds
//   W[ks*32 + (lane>>4)*8 + j][nt*16 + (lane&15)]
#define W1ELTS (22*4096)     // 90112  : w_in
#define A2ELTS (4*4*4096)    // 65536  : A_w (4 layers x 4 k-chunks)
#define PRESPLIT_FLOATS ((2*W1ELTS + 2*A2ELTS)/2)   // 155648 floats = 622592 B

typedef __attribute__((ext_vector_type(8))) short  bfrag;   // 8 bf16 (4 VGPR)
typedef __attribute__((ext_vector_type(4))) float  f32x4;   // MFMA C/D

// f32 -> bf16 (RNE) bit helpers
__device__ __forceinline__ unsigned short f2bf(float f) {
    unsigned int u = __float_as_uint(f);
    return (unsigned short)((u + 0x7fffu + ((u >> 16) & 1u)) >> 16);
}
__device__ __forceinline__ float bf2f(unsigned short h) {
    return __uint_as_float(((unsigned int)h) << 16);
}
__device__ __forceinline__ void split2(float v, unsigned short& hi, unsigned short& lo) {
    hi = f2bf(v);
    lo = f2bf(v - bf2f(hi));
}

// ---------------------------------------------------------------------------
// K0: one-time pre-split of w_in and A_w into lane-linear MFMA B-fragment
// tiles: flat = ((ks*8 + nt)*64 + lane)*8 + j,  lane = kg*16 + l15,
// holding W[ks*32 + kg*8 + j][nt*16 + l15].
// Grid 608*256 == 90112 + 65536 exactly.
// ---------------------------------------------------------------------------
__global__ __launch_bounds__(256)
void k0_presplit(const float* __restrict__ w, const float* __restrict__ Aw,
                 unsigned short* __restrict__ w1hi, unsigned short* __restrict__ w1lo,
                 unsigned short* __restrict__ a2hi, unsigned short* __restrict__ a2lo)
{
    const int f = blockIdx.x * 256 + threadIdx.x;
    if (f < W1ELTS) {
        const int ks = f >> 12, r = f & 4095;
        const int nt = r >> 9, wfl = r & 511;
        const int lane = wfl >> 3, j = wfl & 7;
        const int kg = lane >> 4, l15 = lane & 15;
        const int k = ks * 32 + kg * 8 + j, n = nt * 16 + l15;
        const float v = (k < DIN_) ? w[(long)k * HID_ + n] : 0.f;
        unsigned short hi, lo; split2(v, hi, lo);
        w1hi[f] = hi; w1lo[f] = lo;
    } else {
        const int g = f - W1ELTS;              // 0..65535
        const int l = g >> 14, r2 = g & 16383;
        const int ks = r2 >> 12, r = r2 & 4095;
        const int nt = r >> 9, wfl = r & 511;
        const int lane = wfl >> 3, j = wfl & 7;
        const int kg = lane >> 4, l15 = lane & 15;
        const int k = ks * 32 + kg * 8 + j, n = nt * 16 + l15;
        const float v = Aw[(long)l * 16384 + (long)k * HID_ + n];
        unsigned short hi, lo; split2(v, hi, lo);
        a2hi[g] = hi; a2lo[g] = lo;
    }
}

// ---------------------------------------------------------------------------
// K1 v3 (register fragments, no LDS, 1 m-tile/wave): inp = x @ w_in + b_in.
// Grid 1200 x 256thr; wave owns 16 rows. lb(256,4) for occupancy.
// Split-bf16 3-MFMA sequence (hh, hl, lh) — same accumulation order as the
// round-2 PASSED kernel -> bitwise identical output.
// ---------------------------------------------------------------------------
__global__ __launch_bounds__(256, 4)
void k1_reg(const float* __restrict__ x,
            const unsigned short* __restrict__ whi,
            const unsigned short* __restrict__ wlo,
            const float* __restrict__ bin, float* __restrict__ inp)
{
    const int tid  = threadIdx.x;
    const int wave = tid >> 6;
    const int lane = tid & 63;
    const int l15  = lane & 15;
    const int kg   = lane >> 4;
    const long m0  = (long)blockIdx.x * 64 + wave * 16;

    f32x4 acc[8];
#pragma unroll
    for (int nt = 0; nt < 8; ++nt) {
        const float bv = bin[nt * 16 + l15];
        acc[nt] = (f32x4){bv, bv, bv, bv};
    }

    const int foff = lane * 8;                 // lane-linear tile offset

    for (int ks = 0; ks < 22; ++ks) {
        const int kbase = ks * 32 + kg * 8;

        bfrag ahi, alo;
        const float* __restrict__ xr = x + (m0 + l15) * (long)DIN_ + kbase;
        if (kbase + 7 < DIN_) {
            const float4 p0 = *(const float4*)(xr);
            const float4 p1 = *(const float4*)(xr + 4);
            float vv[8] = {p0.x, p0.y, p0.z, p0.w, p1.x, p1.y, p1.z, p1.w};
#pragma unroll
            for (int j = 0; j < 8; ++j) {
                unsigned short hi, lo; split2(vv[j], hi, lo);
                ahi[j] = (short)hi; alo[j] = (short)lo;
            }
        } else {
#pragma unroll
            for (int j = 0; j < 8; ++j) {
                float v = (kbase + j < DIN_) ? xr[j] : 0.f;
                unsigned short hi, lo; split2(v, hi, lo);
                ahi[j] = (short)hi; alo[j] = (short)lo;
            }
        }

        const unsigned short* __restrict__ wh = whi + (long)ks * 4096 + foff;
        const unsigned short* __restrict__ wl = wlo + (long)ks * 4096 + foff;
#pragma unroll
        for (int nt = 0; nt < 8; ++nt) {
            const bfrag bhi = *(const bfrag*)(wh + nt * 512);
            const bfrag blo = *(const bfrag*)(wl + nt * 512);
            acc[nt] = __builtin_amdgcn_mfma_f32_16x16x32_bf16(ahi, bhi, acc[nt], 0, 0, 0);
            acc[nt] = __builtin_amdgcn_mfma_f32_16x16x32_bf16(ahi, blo, acc[nt], 0, 0, 0);
            acc[nt] = __builtin_amdgcn_mfma_f32_16x16x32_bf16(alo, bhi, acc[nt], 0, 0, 0);
        }
    }

#pragma unroll
    for (int nt = 0; nt < 8; ++nt) {
        const int col = nt * 16 + l15;
#pragma unroll
        for (int reg = 0; reg < 4; ++reg)
            inp[(m0 + kg * 4 + reg) * (long)HID_ + col] = acc[nt][reg];
    }
}

// ---------------------------------------------------------------------------
// K2 v3 (register fragments, no LDS, 1 m-tile/wave, grid 1200):
// xs[l] = inp @ A_w[l] + A_b[l] for all 4 layers per block.
// A(inp) fragments hoisted out of the layer loop (layer-invariant).
// Weight panels (256 KB total) stay L2-hot: every CU re-reads them densely.
// ---------------------------------------------------------------------------
__global__ __launch_bounds__(256, 4)
void k2_reg(const float* __restrict__ inp,
            const unsigned short* __restrict__ ahiP,
            const unsigned short* __restrict__ aloP,
            const float* __restrict__ Ab, float* __restrict__ xs)
{
    const int tid  = threadIdx.x;
    const int wave = tid >> 6;
    const int lane = tid & 63;
    const int l15  = lane & 15;
    const int kg   = lane >> 4;
    const long m0  = (long)blockIdx.x * 64 + wave * 16;
    const int foff = lane * 8;

    // ---- hoisted A fragments: inp[m0+l15][0..127], split hi/lo (32 VGPRs)
    bfrag xhi[4], xlo[4];
#pragma unroll
    for (int ks = 0; ks < 4; ++ks) {
        const float* __restrict__ ir = inp + (m0 + l15) * (long)HID_ + ks * 32 + kg * 8;
        const float4 p0 = *(const float4*)(ir);
        const float4 p1 = *(const float4*)(ir + 4);
        float vv[8] = {p0.x, p0.y, p0.z, p0.w, p1.x, p1.y, p1.z, p1.w};
#pragma unroll
        for (int j = 0; j < 8; ++j) {
            unsigned short hi, lo; split2(vv[j], hi, lo);
            xhi[ks][j] = (short)hi; xlo[ks][j] = (short)lo;
        }
    }

    for (int l = 0; l < 4; ++l) {
        f32x4 acc[8];
#pragma unroll
        for (int nt = 0; nt < 8; ++nt) {
            const float bv = Ab[l * HID_ + nt * 16 + l15];
            acc[nt] = (f32x4){bv, bv, bv, bv};
        }

        const unsigned short* __restrict__ ph = ahiP + (long)l * 16384;
        const unsigned short* __restrict__ pl = aloP + (long)l * 16384;

#pragma unroll
        for (int ks = 0; ks < 4; ++ks) {
            const unsigned short* __restrict__ bh = ph + ks * 4096 + foff;
            const unsigned short* __restrict__ bl = pl + ks * 4096 + foff;
#pragma unroll
            for (int nt = 0; nt < 8; ++nt) {
                const bfrag bhi = *(const bfrag*)(bh + nt * 512);
                const bfrag blo = *(const bfrag*)(bl + nt * 512);
                acc[nt] = __builtin_amdgcn_mfma_f32_16x16x32_bf16(xhi[ks], bhi, acc[nt], 0, 0, 0);
                acc[nt] = __builtin_amdgcn_mfma_f32_16x16x32_bf16(xhi[ks], blo, acc[nt], 0, 0, 0);
                acc[nt] = __builtin_amdgcn_mfma_f32_16x16x32_bf16(xlo[ks], bhi, acc[nt], 0, 0, 0);
            }
        }

#pragma unroll
        for (int nt = 0; nt < 8; ++nt) {
            const int col = nt * 16 + l15;
#pragma unroll
            for (int reg = 0; reg < 4; ++reg)
                xs[((long)l * NROWS_ + m0 + kg * 4 + reg) * (long)HID_ + col] = acc[nt][reg];
        }
    }
}

// ---------------------------------------------------------------------------
// K1 (legacy MFMA, LDS-staged) — fallback path only.
// ---------------------------------------------------------------------------
__global__ __launch_bounds__(256, 2)
void k1_mfma(const float* __restrict__ x, const float* __restrict__ w,
             const float* __restrict__ bin, float* __restrict__ inp)
{
    __shared__ unsigned short whi[128 * 40];
    __shared__ unsigned short wlo[128 * 40];

    const int tid  = threadIdx.x;
    const int wave = tid >> 6;
    const int lane = tid & 63;
    const int l15  = lane & 15;
    const int kg   = lane >> 4;
    const long m0  = (long)blockIdx.x * 64 + wave * 16;
    const long arow = m0 + l15;

    f32x4 acc[8];
#pragma unroll
    for (int nt = 0; nt < 8; ++nt) {
        const float bv = bin[nt * 16 + l15];
        acc[nt] = (f32x4){bv, bv, bv, bv};
    }

    for (int ks = 0; ks < 22; ++ks) {
        const int k0 = ks * 32;
        const int lim = (700 - k0) * 128;
        const float* __restrict__ wsrc = w + (long)k0 * 128;
#pragma unroll
        for (int j = 0; j < 16; ++j) {
            const int i = tid + j * 256;
            const int kk = i >> 7, nn = i & 127;
            float v = (i < lim) ? wsrc[i] : 0.f;
            unsigned short hi, lo;
            split2(v, hi, lo);
            whi[nn * 40 + kk] = hi;
            wlo[nn * 40 + kk] = lo;
        }
        __syncthreads();

        bfrag ahi, alo;
        const int kbase = k0 + kg * 8;
        const float* __restrict__ xr = x + arow * (long)DIN_ + kbase;
        if (kbase + 7 < 700) {
            const float4 p0 = *(const float4*)(xr);
            const float4 p1 = *(const float4*)(xr + 4);
            float vv[8] = {p0.x, p0.y, p0.z, p0.w, p1.x, p1.y, p1.z, p1.w};
#pragma unroll
            for (int j = 0; j < 8; ++j) {
                unsigned short hi, lo; split2(vv[j], hi, lo);
                ahi[j] = (short)hi; alo[j] = (short)lo;
            }
        } else {
#pragma unroll
            for (int j = 0; j < 8; ++j) {
                float v = (kbase + j < 700) ? xr[j] : 0.f;
                unsigned short hi, lo; split2(v, hi, lo);
                ahi[j] = (short)hi; alo[j] = (short)lo;
            }
        }

#pragma unroll
        for (int nt = 0; nt < 8; ++nt) {
            const int boff = (nt * 16 + l15) * 40 + kg * 8;
            const bfrag bhi = *(const bfrag*)&whi[boff];
            const bfrag blo = *(const bfrag*)&wlo[boff];
            acc[nt] = __builtin_amdgcn_mfma_f32_16x16x32_bf16(ahi, bhi, acc[nt], 0, 0, 0);
            acc[nt] = __builtin_amdgcn_mfma_f32_16x16x32_bf16(ahi, blo, acc[nt], 0, 0, 0);
            acc[nt] = __builtin_amdgcn_mfma_f32_16x16x32_bf16(alo, bhi, acc[nt], 0, 0, 0);
        }
        __syncthreads();
    }

#pragma unroll
    for (int nt = 0; nt < 8; ++nt) {
        const int col = nt * 16 + l15;
#pragma unroll
        for (int reg = 0; reg < 4; ++reg)
            inp[(m0 + kg * 4 + reg) * (long)HID_ + col] = acc[nt][reg];
    }
}

// ---------------------------------------------------------------------------
// K2 (legacy MFMA, LDS-staged) — fallback path only.
// ---------------------------------------------------------------------------
__global__ __launch_bounds__(256, 2)
void k2_mfma(const float* __restrict__ inp, const float* __restrict__ Aw,
             const float* __restrict__ Ab, float* __restrict__ xs,
             int lsel, long lstride)
{
    __shared__ unsigned short ahiS[128 * 72];
    __shared__ unsigned short aloS[128 * 72];

    const int tid  = threadIdx.x;
    const int wave = tid >> 6;
    const int lane = tid & 63;
    const int l15  = lane & 15;
    const int kg   = lane >> 4;
    const int l    = (lsel >= 0) ? lsel : (int)blockIdx.y;
    const long m0  = (long)blockIdx.x * 64 + wave * 16;
    const long arow = m0 + l15;
    const long lbase = (lsel >= 0) ? 0 : (long)l * lstride;

    f32x4 acc[8];
#pragma unroll
    for (int nt = 0; nt < 8; ++nt) {
        const float bv = Ab[l * 128 + nt * 16 + l15];
        acc[nt] = (f32x4){bv, bv, bv, bv};
    }

    const float* __restrict__ Al = Aw + (long)l * 128 * 128;

    for (int kc = 0; kc < 2; ++kc) {
        const float* __restrict__ asrc = Al + (long)kc * 64 * 128;
#pragma unroll
        for (int j = 0; j < 32; ++j) {
            const int i = tid + j * 256;
            const int kk = i >> 7, nn = i & 127;
            unsigned short hi, lo;
            split2(asrc[i], hi, lo);
            ahiS[nn * 72 + kk] = hi;
            aloS[nn * 72 + kk] = lo;
        }
        __syncthreads();

#pragma unroll
        for (int ks = 0; ks < 2; ++ks) {
            const int k0 = kc * 64 + ks * 32;
            bfrag ahi, alo;
            const float* __restrict__ ir = inp + arow * (long)HID_ + k0 + kg * 8;
            const float4 p0 = *(const float4*)(ir);
            const float4 p1 = *(const float4*)(ir + 4);
            float vv[8] = {p0.x, p0.y, p0.z, p0.w, p1.x, p1.y, p1.z, p1.w};
#pragma unroll
            for (int j = 0; j < 8; ++j) {
                unsigned short hi, lo; split2(vv[j], hi, lo);
                ahi[j] = (short)hi; alo[j] = (short)lo;
            }

#pragma unroll
            for (int nt = 0; nt < 8; ++nt) {
                const int boff = (nt * 16 + l15) * 72 + ks * 32 + kg * 8;
                const bfrag bhi = *(const bfrag*)&ahiS[boff];
                const bfrag blo = *(const bfrag*)&aloS[boff];
                acc[nt] = __builtin_amdgcn_mfma_f32_16x16x32_bf16(ahi, bhi, acc[nt], 0, 0, 0);
                acc[nt] = __builtin_amdgcn_mfma_f32_16x16x32_bf16(ahi, blo, acc[nt], 0, 0, 0);
                acc[nt] = __builtin_amdgcn_mfma_f32_16x16x32_bf16(alo, bhi, acc[nt], 0, 0, 0);
            }
        }
        __syncthreads();
    }

#pragma unroll
    for (int nt = 0; nt < 8; ++nt) {
        const int col = nt * 16 + l15;
#pragma unroll
        for (int reg = 0; reg < 4; ++reg)
            xs[(lbase + m0 + kg * 4 + reg) * (long)HID_ + col] = acc[nt][reg];
    }
}

// ---------------------------------------------------------------------------
// K3': elementwise scan over t. 20 loads in flight per iter.
// ---------------------------------------------------------------------------
__global__ __launch_bounds__(128, 4)
void k3_scan_split(const float* __restrict__ xs, const float* __restrict__ thr,
                   const float* __restrict__ dec, const float* __restrict__ rstv,
                   const float* __restrict__ mem0, float* __restrict__ rates,
                   float* __restrict__ omem, float* __restrict__ ospk,
                   int lsel, long lstride)
{
    const int h = threadIdx.x;
    int l, b;
    if (lsel >= 0) { l = lsel; b = blockIdx.x; }
    else           { l = blockIdx.x >> 8; b = blockIdx.x & 255; }

    const float th = thr[h];
    const float dc = dec[h];
    const float rs = rstv[h];

    float mem = mem0[((long)l * 256 + b) * 128 + h];
    float spk = 0.f;
    float cnt = 0.f;

    const bool last = (l == 3);
    float* __restrict__ om = omem + (long)b * 301 * 128 + h;
    float* __restrict__ os = ospk + (long)b * 301 * 128 + h;
    if (last) { om[0] = mem; os[0] = 0.f; }

    const float* __restrict__ p =
        xs + ((lsel >= 0 ? 0L : (long)l * lstride) + (long)b * TT_) * HID_ + h;

    for (int t0 = 0; t0 < TT_; t0 += 20) {
        float v[20];
#pragma unroll
        for (int j = 0; j < 20; ++j) v[j] = p[(long)(t0 + j) * HID_];
#pragma unroll
        for (int j = 0; j < 20; ++j) {
            mem = rs * spk + mem * dc * (1.f - spk) + v[j];
            spk = (mem - th > 0.f) ? 1.f : 0.f;
            cnt += spk;
            if (last) {
                om[(long)(t0 + j + 1) * 128] = mem;
                os[(long)(t0 + j + 1) * 128] = spk;
            }
        }
    }

    rates[((long)l * 256 + b) * 128 + h] = cnt * (1.f / 300.f);
}

// ---------------------------------------------------------------------------
// Legacy fused drive+scan (fallback when ws is tiny).
// ---------------------------------------------------------------------------
__global__ __launch_bounds__(128, 2)
void k3_fused(const float* __restrict__ inp, const float* __restrict__ Aw,
              const float* __restrict__ Ab, const float* __restrict__ thr,
              const float* __restrict__ dec, const float* __restrict__ rstv,
              const float* __restrict__ mem0, float* __restrict__ rates,
              float* __restrict__ omem, float* __restrict__ ospk)
{
    const int h = threadIdx.x;
    const int l = blockIdx.x & 3;
    const int b = blockIdx.x >> 2;

    float a[128];
#pragma unroll
    for (int k = 0; k < 128; ++k)
        a[k] = Aw[((long)l * 128 + k) * 128 + h];

    const float ab = Ab[l * 128 + h];
    const float th = thr[h];
    const float dc = dec[h];
    const float rs = rstv[h];

    float mem = mem0[((long)l * 256 + b) * 128 + h];
    float spk = 0.f, cnt = 0.f;

    const bool last = (l == 3);
    float* __restrict__ om = omem + (long)b * 301 * 128 + h;
    float* __restrict__ os = ospk + (long)b * 301 * 128 + h;
    if (last) { om[0] = mem; os[0] = 0.f; }

    const float* __restrict__ ip = inp + (long)b * 300 * 128;

    for (int t = 0; t < 300; ++t) {
        float acc = ab;
#pragma unroll
        for (int k = 0; k < 128; ++k)
            acc = fmaf(ip[k], a[k], acc);
        ip += 128;
        mem = rs * spk + mem * dc * (1.f - spk) + acc;
        spk = (mem - th > 0.f) ? 1.f : 0.f;
        cnt += spk;
        if (last) {
            om[(long)(t + 1) * 128] = mem;
            os[(long)(t + 1) * 128] = spk;
        }
    }
    rates[((long)l * 256 + b) * 128 + h] = cnt * (1.f / 300.f);
}

// ---------------------------------------------------------------------------
// K4: head. block per batch row b.
// ---------------------------------------------------------------------------
__global__ __launch_bounds__(256)
void k4_head(const float* __restrict__ rates, const float* __restrict__ fcw,
             const float* __restrict__ fcb, const float* __restrict__ wout,
             const float* __restrict__ bout, float* __restrict__ out)
{
    __shared__ float cat[512];
    const int b = blockIdx.x;
    const int tid = threadIdx.x;

    for (int c = tid; c < 512; c += 256) {
        const int l = c >> 7;
        const int k = c & 127;
        float s = fcb[l * 128 + k];
        const float* __restrict__ rp = rates + ((long)l * 256 + b) * 128;
        const float* __restrict__ wp = fcw + (long)l * 128 * 128 + k;
#pragma unroll 8
        for (int hh = 0; hh < 128; ++hh)
            s = fmaf(rp[hh], wp[(long)hh * 128], s);
        cat[c] = s > 0.f ? s : 0.f;
    }
    __syncthreads();

    if (tid < NOUT_) {
        float s = bout[tid];
#pragma unroll 8
        for (int c = 0; c < 512; ++c)
            s = fmaf(cat[c], wout[(long)c * NOUT_ + tid], s);
        out[(long)b * NOUT_ + tid] = s;
    }
}

// ---------------------------------------------------------------------------
// K5: A_norm = sum |A_w|. Single block.
// ---------------------------------------------------------------------------
__global__ __launch_bounds__(256)
void k5_anorm(const float* __restrict__ Aw, float* __restrict__ out)
{
    __shared__ float red[256];
    const int tid = threadIdx.x;
    float s = 0.f;
    for (int i = tid; i < LL_ * 128 * 128; i += 256)
        s += fabsf(Aw[i]);
    red[tid] = s;
    __syncthreads();
#pragma unroll
    for (int st = 128; st > 0; st >>= 1) {
        if (tid < st) red[tid] += red[tid + st];
        __syncthreads();
    }
    if (tid == 0) out[0] = red[0];
}

// ---------------------------------------------------------------------------
extern "C" void kernel_launch(void* const* d_in, const int* in_sizes, int n_in,
                              void* d_out, int out_size, void* d_ws, size_t ws_size,
                              hipStream_t stream)
{
    const float* x    = (const float*)d_in[0];
    const float* w_in = (const float*)d_in[1];
    const float* b_in = (const float*)d_in[2];
    const float* A_w  = (const float*)d_in[3];
    const float* A_b  = (const float*)d_in[4];
    const float* fc_w = (const float*)d_in[5];
    const float* fc_b = (const float*)d_in[6];
    const float* w_out= (const float*)d_in[7];
    const float* b_out= (const float*)d_in[8];
    const float* thr  = (const float*)d_in[9];
    const float* dec  = (const float*)d_in[10];
    const float* rst  = (const float*)d_in[11];
    const float* mem0 = (const float*)d_in[12];

    float* out = (float*)d_out;
    float* ws  = (float*)d_ws;

    const long INP_ELTS = (long)NROWS_ * HID_;
    const long XS_FULL  = 4L * NROWS_ * HID_;
    const long RATES    = 4L * 256 * 128;

    const size_t need_v4   = (size_t)(PRESPLIT_FLOATS + INP_ELTS + XS_FULL + RATES) * 4;
    const size_t need_full = (size_t)(INP_ELTS + XS_FULL + RATES) * 4;
    const size_t need_perl = (size_t)(INP_ELTS + INP_ELTS + RATES) * 4;

    if (ws_size >= need_v4) {
        // --- v4 path: pre-split weights + LDS-free register-fragment GEMMs ---
        unsigned short* us   = (unsigned short*)ws;
        unsigned short* w1hi = us;
        unsigned short* w1lo = us + W1ELTS;
        unsigned short* a2hi = us + 2 * W1ELTS;
        unsigned short* a2lo = us + 2 * W1ELTS + A2ELTS;
        float* inp   = ws + PRESPLIT_FLOATS;
        float* xs    = inp + INP_ELTS;
        float* rates = xs + XS_FULL;

        k0_presplit<<<608, 256, 0, stream>>>(w_in, A_w, w1hi, w1lo, a2hi, a2lo);
        k1_reg<<<1200, 256, 0, stream>>>(x, w1hi, w1lo, b_in, inp);
        k2_reg<<<1200, 256, 0, stream>>>(inp, a2hi, a2lo, A_b, xs);
        k3_scan_split<<<1024, 128, 0, stream>>>(xs, thr, dec, rst, mem0, rates,
                                                out + HMEM_OFF, out + HSPK_OFF,
                                                -1, (long)NROWS_);
        k4_head<<<256, 256, 0, stream>>>(rates, fc_w, fc_b, w_out, b_out, out + OUT_OFF);
    } else if (ws_size >= need_full) {
        float* inp   = ws;
        float* xs    = ws + INP_ELTS;
        float* rates = xs + XS_FULL;
        k1_mfma<<<1200, 256, 0, stream>>>(x, w_in, b_in, inp);
        k2_mfma<<<dim3(1200, 4), 256, 0, stream>>>(inp, A_w, A_b, xs, -1, (long)NROWS_);
        k3_scan_split<<<1024, 128, 0, stream>>>(xs, thr, dec, rst, mem0, rates,
                                                out + HMEM_OFF, out + HSPK_OFF,
                                                -1, (long)NROWS_);
        k4_head<<<256, 256, 0, stream>>>(rates, fc_w, fc_b, w_out, b_out, out + OUT_OFF);
    } else if (ws_size >= need_perl) {
        float* inp   = ws;
        float* xs    = ws + INP_ELTS;
        float* rates = xs + INP_ELTS;
        k1_mfma<<<1200, 256, 0, stream>>>(x, w_in, b_in, inp);
        for (int l = 0; l < 4; ++l) {
            k2_mfma<<<dim3(1200, 1), 256, 0, stream>>>(inp, A_w, A_b, xs, l, 0L);
            k3_scan_split<<<256, 128, 0, stream>>>(xs, thr, dec, rst, mem0, rates,
                                                   out + HMEM_OFF, out + HSPK_OFF,
                                                   l, 0L);
        }
        k4_head<<<256, 256, 0, stream>>>(rates, fc_w, fc_b, w_out, b_out, out + OUT_OFF);
    } else {
        float* inp   = ws;
        float* rates = ws + INP_ELTS;
        k1_mfma<<<1200, 256, 0, stream>>>(x, w_in, b_in, inp);
        k3_fused<<<1024, 128, 0, stream>>>(inp, A_w, A_b, thr, dec, rst, mem0,
                                           rates, out + HMEM_OFF, out + HSPK_OFF);
        k4_head<<<256, 256, 0, stream>>>(rates, fc_w, fc_b, w_out, b_out, out + OUT_OFF);
    }

    k5_anorm<<<1, 256, 0, stream>>>(A_w, out + ANORM_OFF);
}